// Round 8
// baseline (145.390 us; speedup 1.0000x reference)
//
#include <hip/hip_runtime.h>

#define SIZE 128
#define PADW 136   // LDS row pitch in bf16 elements; breaks pow2 stride

typedef short short8 __attribute__((ext_vector_type(8)));
typedef float f32x4 __attribute__((ext_vector_type(4)));

__device__ __forceinline__ unsigned short f2bf(float f) {
    unsigned int u = __float_as_uint(f);
    unsigned int r = u + 0x7FFFu + ((u >> 16) & 1u);
    return (unsigned short)(r >> 16);
}
__device__ __forceinline__ float bf2f(unsigned short h) {
    return __uint_as_float(((unsigned int)h) << 16);
}

// gr = Re(ifft(b)). Folds DyT affine params into the conv matrix:
//   Gt[c][k] = w[k] * gr[(c-k)&127]   (bf16, 32 KB)
//   C0[c]    = sum_k bias[k] * gr[(c-k)&127]   (f32, 512 B at offset 32768)
__global__ void build_gt(const float* __restrict__ br, const float* __restrict__ bi,
                         const float* __restrict__ w, const float* __restrict__ bias,
                         unsigned short* __restrict__ Gt, float* __restrict__ C0) {
    __shared__ float gr[SIZE];
    const int t = threadIdx.x;  // 0..127
    float acc = 0.0f;
    for (int j = 0; j < SIZE; ++j) {
        int p = (j * t) & 127;                 // exact periodic reduction
        float a = (float)p * (1.0f / 64.0f);   // angle in units of pi
        acc += br[j] * cospif(a) - bi[j] * sinpif(a);
    }
    gr[t] = acc * (1.0f / 128.0f);
    __syncthreads();
    float c0 = 0.0f;
    for (int k = 0; k < SIZE; ++k) {
        const float g = gr[(t - k) & 127];
        c0 += bias[k] * g;
        Gt[t * SIZE + k] = f2bf(w[k] * g);
    }
    C0[t] = c0;
}

// out[r][c] = sum_k tanh(alpha*x[r][k]) * Gt[c][k] + C0[c] + x[r][c]
// BARRIER-FREE: wave w of each block owns rows [16w, 16w+16) of a 64-row
// tile — staging, LDS h, MFMA, LDS o, epilogue are all wave-local, ordered
// only by the wave's own lgkmcnt waits. 4 independent streaming waves per
// block; 4096 blocks; launch_bounds(256,5) -> 5 blocks (20 waves) per CU.
// All global I/O is lane-contiguous (1 KB / wave-instruction).
__global__ __launch_bounds__(256, 5) void fourier_main(
    const float* __restrict__ x, const float* __restrict__ alpha_p,
    const unsigned short* __restrict__ Gt, const float* __restrict__ C0,
    float* __restrict__ out) {
    __shared__ unsigned short hS[4][16][PADW];  // per-wave 16x128 bf16 slice

    const int tid = threadIdx.x;
    const int lane = tid & 63;
    const int wv = tid >> 6;       // wave id = row band
    const int lrow = lane & 15;    // fragment row within band
    const int slot = lane >> 4;    // fragment k-chunk / col-group selector

    const float a2 = 2.0f * alpha_p[0];

    // this wave's 16x128 band: 8 KB contiguous in global
    const unsigned base =
        (unsigned)blockIdx.x * (64u * SIZE) + (unsigned)wv * (16u * SIZE);
    const int rl = lane >> 5;        // linear map: row = 2j + rl
    const int cl = (lane & 31) * 4;  //             col = cl

    // ---- 1. contiguous x loads (kept in regs for the residual) ----
    float4 xr[8];
#pragma unroll
    for (int j = 0; j < 8; ++j)
        xr[j] = *reinterpret_cast<const float4*>(&x[base + j * 256 + lane * 4]);

    // ---- 2. h = tanh(alpha*x) -> bf16 -> own LDS slice ----
    // tanh(t) = 1 - 2/(1+e^{2t})
#pragma unroll
    for (int j = 0; j < 8; ++j) {
        ushort4 hq;
        float e, r;
        e = __expf(a2 * xr[j].x); r = __builtin_amdgcn_rcpf(1.0f + e);
        hq.x = f2bf(fmaf(-2.0f, r, 1.0f));
        e = __expf(a2 * xr[j].y); r = __builtin_amdgcn_rcpf(1.0f + e);
        hq.y = f2bf(fmaf(-2.0f, r, 1.0f));
        e = __expf(a2 * xr[j].z); r = __builtin_amdgcn_rcpf(1.0f + e);
        hq.z = f2bf(fmaf(-2.0f, r, 1.0f));
        e = __expf(a2 * xr[j].w); r = __builtin_amdgcn_rcpf(1.0f + e);
        hq.w = f2bf(fmaf(-2.0f, r, 1.0f));
        *reinterpret_cast<ushort4*>(&hS[wv][2 * j + rl][cl]) = hq;
    }

    // ---- 3. h fragments for this band (wave-local, lgkmcnt-ordered) ----
    short8 hf[4];
#pragma unroll
    for (int kt = 0; kt < 4; ++kt)
        hf[kt] = *reinterpret_cast<const short8*>(
            &hS[wv][lrow][kt * 32 + slot * 8]);

    // ---- 4. conv: 8 N-tiles; G frags from L2-hot Gt; o -> same LDS slice ----
    // (safe overwrite: all hf consumed above before first o write)
#pragma unroll
    for (int nt = 0; nt < 8; ++nt) {
        short8 gf[4];
#pragma unroll
        for (int kt = 0; kt < 4; ++kt)
            gf[kt] = *reinterpret_cast<const short8*>(
                &Gt[(nt * 16 + lrow) * SIZE + kt * 32 + slot * 8]);
        const float4 c0v = *reinterpret_cast<const float4*>(&C0[nt * 16 + slot * 4]);
        f32x4 a = {0.f, 0.f, 0.f, 0.f};
#pragma unroll
        for (int kt = 0; kt < 4; ++kt)
            a = __builtin_amdgcn_mfma_f32_16x16x32_bf16(gf[kt], hf[kt], a, 0, 0, 0);
        // D: row = lrow (this band), cols = nt*16 + slot*4 + reg
        ushort4 o;
        o.x = f2bf(a[0] + c0v.x);
        o.y = f2bf(a[1] + c0v.y);
        o.z = f2bf(a[2] + c0v.z);
        o.w = f2bf(a[3] + c0v.w);
        *reinterpret_cast<ushort4*>(&hS[wv][lrow][nt * 16 + slot * 4]) = o;
    }

    // ---- 5. epilogue: linear LDS read, add residual, contiguous store ----
#pragma unroll
    for (int j = 0; j < 8; ++j) {
        const ushort4 ov =
            *reinterpret_cast<const ushort4*>(&hS[wv][2 * j + rl][cl]);
        float4 r;
        r.x = bf2f(ov.x) + xr[j].x;
        r.y = bf2f(ov.y) + xr[j].y;
        r.z = bf2f(ov.z) + xr[j].z;
        r.w = bf2f(ov.w) + xr[j].w;
        *reinterpret_cast<float4*>(&out[base + j * 256 + lane * 4]) = r;
    }
}

extern "C" void kernel_launch(void* const* d_in, const int* in_sizes, int n_in,
                              void* d_out, int out_size, void* d_ws, size_t ws_size,
                              hipStream_t stream) {
    const float* x = (const float*)d_in[0];
    const float* alpha = (const float*)d_in[1];
    const float* dyt_w = (const float*)d_in[2];
    const float* dyt_b = (const float*)d_in[3];
    // d_in[4] = a_real, d_in[5] = a_imag, d_in[8] = ffn_bias: dead code in reference
    const float* b_real = (const float*)d_in[6];
    const float* b_imag = (const float*)d_in[7];
    float* out = (float*)d_out;

    unsigned short* Gt = (unsigned short*)d_ws;            // 32 KB bf16
    float* C0 = (float*)((char*)d_ws + SIZE * SIZE * 2);   // 512 B f32

    build_gt<<<1, 128, 0, stream>>>(b_real, b_imag, dyt_w, dyt_b, Gt, C0);

    const int rows = out_size / SIZE;   // 262144
    const int nblocks = rows / 64;      // 4096
    fourier_main<<<nblocks, 256, 0, stream>>>(x, alpha, Gt, C0, out);
}

// Round 9
// 136.292 us; speedup vs baseline: 1.0668x; 1.0668x over previous
//
#include <hip/hip_runtime.h>

#define SIZE 128
#define PADW 136   // LDS row pitch in bf16 elements; breaks pow2 stride

typedef short short8 __attribute__((ext_vector_type(8)));
typedef float f32x4 __attribute__((ext_vector_type(4)));

__device__ __forceinline__ unsigned short f2bf(float f) {
    unsigned int u = __float_as_uint(f);
    unsigned int r = u + 0x7FFFu + ((u >> 16) & 1u);
    return (unsigned short)(r >> 16);
}
__device__ __forceinline__ float bf2f(unsigned short h) {
    return __uint_as_float(((unsigned int)h) << 16);
}

// gr = Re(ifft(b)). Folds DyT affine params into the conv matrix:
//   Gt[c][k] = w[k] * gr[(c-k)&127]   (bf16, 32 KB)
//   C0[c]    = sum_k bias[k] * gr[(c-k)&127]   (f32, 512 B at offset 32768)
__global__ void build_gt(const float* __restrict__ br, const float* __restrict__ bi,
                         const float* __restrict__ w, const float* __restrict__ bias,
                         unsigned short* __restrict__ Gt, float* __restrict__ C0) {
    __shared__ float gr[SIZE];
    const int t = threadIdx.x;  // 0..127
    float acc = 0.0f;
    for (int j = 0; j < SIZE; ++j) {
        int p = (j * t) & 127;                 // exact periodic reduction
        float a = (float)p * (1.0f / 64.0f);   // angle in units of pi
        acc += br[j] * cospif(a) - bi[j] * sinpif(a);
    }
    gr[t] = acc * (1.0f / 128.0f);
    __syncthreads();
    float c0 = 0.0f;
    for (int k = 0; k < SIZE; ++k) {
        const float g = gr[(t - k) & 127];
        c0 += bias[k] * g;
        Gt[t * SIZE + k] = f2bf(w[k] * g);
    }
    C0[t] = c0;
}

// out[r][c] = sum_k tanh(alpha*x[r][k]) * Gt[c][k] + C0[c] + x[r][c]
// R7 structure (linear global I/O, LDS bounce, wave w owns output cols
// [32w,32w+32)) with the output bounce buffer HALVED: conv results for 32
// rows at a time go through oA (8.7 KB), two MFMA/epilogue half-passes,
// 4 barriers. LDS 26112 B/block -> 6 resident blocks/CU (vs R7's 4).
__global__ __launch_bounds__(256, 6) void fourier_main(
    const float* __restrict__ x, const float* __restrict__ alpha_p,
    const unsigned short* __restrict__ Gt, const float* __restrict__ C0,
    float* __restrict__ out) {
    __shared__ unsigned short hA[64 * PADW];  // bf16 tanh(alpha*x), full tile
    __shared__ unsigned short oA[32 * PADW];  // bf16 conv+C0, half tile bounce

    const int tid = threadIdx.x;
    const int lane = tid & 63;
    const int wid = tid >> 6;
    const int lrow = lane & 15;   // fragment row selector
    const int slot = lane >> 4;   // fragment k-chunk / col-group selector
    const int colb = wid * 32;

    const float a2 = 2.0f * alpha_p[0];
    const unsigned base = (unsigned)blockIdx.x * (64u * SIZE);  // max 33.5M < 2^31

    // linear map: thread tid, pass j <-> tile row j*8 + rl, cols cl..cl+3
    const int rl = tid >> 5;        // 0..7
    const int cl = (tid & 31) * 4;  // 0..124

    // ---- 1. contiguous x loads (kept in regs for the residual) ----
    float4 xr[8];
#pragma unroll
    for (int j = 0; j < 8; ++j)
        xr[j] = *reinterpret_cast<const float4*>(&x[base + j * 1024 + tid * 4]);

    // ---- 2. h = tanh(alpha*x) -> bf16 -> hA;  tanh(t) = 1 - 2/(1+e^{2t}) ----
#pragma unroll
    for (int j = 0; j < 8; ++j) {
        ushort4 hq;
        float e, r;
        e = __expf(a2 * xr[j].x); r = __builtin_amdgcn_rcpf(1.0f + e);
        hq.x = f2bf(fmaf(-2.0f, r, 1.0f));
        e = __expf(a2 * xr[j].y); r = __builtin_amdgcn_rcpf(1.0f + e);
        hq.y = f2bf(fmaf(-2.0f, r, 1.0f));
        e = __expf(a2 * xr[j].z); r = __builtin_amdgcn_rcpf(1.0f + e);
        hq.z = f2bf(fmaf(-2.0f, r, 1.0f));
        e = __expf(a2 * xr[j].w); r = __builtin_amdgcn_rcpf(1.0f + e);
        hq.w = f2bf(fmaf(-2.0f, r, 1.0f));
        *reinterpret_cast<ushort4*>(&hA[(j * 8 + rl) * PADW + cl]) = hq;
    }

    // ---- G fragments (8 KB/wave, L2-resident) + C0 for this wave's cols ----
    short8 gf[2][4];
    float4 c0v[2];
#pragma unroll
    for (int nt = 0; nt < 2; ++nt) {
        const int c = colb + nt * 16 + lrow;
#pragma unroll
        for (int kt = 0; kt < 4; ++kt)
            gf[nt][kt] = *reinterpret_cast<const short8*>(
                &Gt[c * SIZE + kt * 32 + slot * 8]);
        c0v[nt] = *reinterpret_cast<const float4*>(&C0[colb + nt * 16 + slot * 4]);
    }

    __syncthreads();  // B1: hA published

    // half-pass: MFMA rows [r0, r0+32) -> oA, then linear epilogue of the half
    auto conv_half = [&](int mt0) __attribute__((always_inline)) {
#pragma unroll
        for (int mt = mt0; mt < mt0 + 2; ++mt) {
            short8 hf[4];
#pragma unroll
            for (int kt = 0; kt < 4; ++kt)
                hf[kt] = *reinterpret_cast<const short8*>(
                    &hA[(mt * 16 + lrow) * PADW + kt * 32 + slot * 8]);
#pragma unroll
            for (int nt = 0; nt < 2; ++nt) {
                f32x4 a = {0.f, 0.f, 0.f, 0.f};
#pragma unroll
                for (int kt = 0; kt < 4; ++kt)
                    a = __builtin_amdgcn_mfma_f32_16x16x32_bf16(gf[nt][kt], hf[kt],
                                                                a, 0, 0, 0);
                // D: row = 16mt + lrow; cols = colb + 16nt + 4*slot + reg
                ushort4 o;
                o.x = f2bf(a[0] + c0v[nt].x);
                o.y = f2bf(a[1] + c0v[nt].y);
                o.z = f2bf(a[2] + c0v[nt].z);
                o.w = f2bf(a[3] + c0v[nt].w);
                *reinterpret_cast<ushort4*>(
                    &oA[((mt - mt0) * 16 + lrow) * PADW + colb + nt * 16 +
                        slot * 4]) = o;
            }
        }
    };
    auto epi_half = [&](int j0) __attribute__((always_inline)) {
#pragma unroll
        for (int j = j0; j < j0 + 4; ++j) {
            const ushort4 ov = *reinterpret_cast<const ushort4*>(
                &oA[((j - j0) * 8 + rl) * PADW + cl]);
            float4 r;
            r.x = bf2f(ov.x) + xr[j].x;
            r.y = bf2f(ov.y) + xr[j].y;
            r.z = bf2f(ov.z) + xr[j].z;
            r.w = bf2f(ov.w) + xr[j].w;
            *reinterpret_cast<float4*>(&out[base + j * 1024 + tid * 4]) = r;
        }
    };

    conv_half(0);          // rows 0..31 -> oA
    __syncthreads();       // B2: oA(half 0) published
    epi_half(0);           // store out rows 0..31
    __syncthreads();       // B3: all oA reads retired before overwrite
    conv_half(2);          // rows 32..63 -> oA
    __syncthreads();       // B4: oA(half 1) published
    epi_half(4);           // store out rows 32..63
}

extern "C" void kernel_launch(void* const* d_in, const int* in_sizes, int n_in,
                              void* d_out, int out_size, void* d_ws, size_t ws_size,
                              hipStream_t stream) {
    const float* x = (const float*)d_in[0];
    const float* alpha = (const float*)d_in[1];
    const float* dyt_w = (const float*)d_in[2];
    const float* dyt_b = (const float*)d_in[3];
    // d_in[4] = a_real, d_in[5] = a_imag, d_in[8] = ffn_bias: dead code in reference
    const float* b_real = (const float*)d_in[6];
    const float* b_imag = (const float*)d_in[7];
    float* out = (float*)d_out;

    unsigned short* Gt = (unsigned short*)d_ws;            // 32 KB bf16
    float* C0 = (float*)((char*)d_ws + SIZE * SIZE * 2);   // 512 B f32

    build_gt<<<1, 128, 0, stream>>>(b_real, b_imag, dyt_w, dyt_b, Gt, C0);

    const int rows = out_size / SIZE;   // 262144
    const int nblocks = rows / 64;      // 4096
    fourier_main<<<nblocks, 256, 0, stream>>>(x, alpha, Gt, C0, out);
}

// Round 10
// 71.486 us; speedup vs baseline: 2.0338x; 1.9065x over previous
//
#include <hip/hip_runtime.h>

#define SIZE 128
#define PADW 136   // LDS row pitch in bf16 elements; breaks pow2 stride

typedef short short8 __attribute__((ext_vector_type(8)));
typedef float f32x4 __attribute__((ext_vector_type(4)));

__device__ __forceinline__ unsigned short f2bf(float f) {
    unsigned int u = __float_as_uint(f);
    unsigned int r = u + 0x7FFFu + ((u >> 16) & 1u);
    return (unsigned short)(r >> 16);
}
__device__ __forceinline__ float bf2f(unsigned short h) {
    return __uint_as_float(((unsigned int)h) << 16);
}

// gr = Re(ifft(b)). Folds DyT affine params into the conv matrix:
//   Gt[c][k] = w[k] * gr[(c-k)&127]   (bf16, 32 KB)
//   C0[c]    = sum_k bias[k] * gr[(c-k)&127]   (f32, 512 B at offset 32768)
__global__ void build_gt(const float* __restrict__ br, const float* __restrict__ bi,
                         const float* __restrict__ w, const float* __restrict__ bias,
                         unsigned short* __restrict__ Gt, float* __restrict__ C0) {
    __shared__ float gr[SIZE];
    const int t = threadIdx.x;  // 0..127
    float acc = 0.0f;
    for (int j = 0; j < SIZE; ++j) {
        int p = (j * t) & 127;                 // exact periodic reduction
        float a = (float)p * (1.0f / 64.0f);   // angle in units of pi
        acc += br[j] * cospif(a) - bi[j] * sinpif(a);
    }
    gr[t] = acc * (1.0f / 128.0f);
    __syncthreads();
    float c0 = 0.0f;
    for (int k = 0; k < SIZE; ++k) {
        const float g = gr[(t - k) & 127];
        c0 += bias[k] * g;
        Gt[t * SIZE + k] = f2bf(w[k] * g);
    }
    C0[t] = c0;
}

// out[r][c] = sum_k tanh(alpha*x[r][k]) * Gt[c][k] + C0[c] + x[r][c]
// R9 structure with the spill-inducing launch_bounds FIXED: (256,4) caps
// VGPR at 128 (kernel needs ~90-110 live; (256,6)'s cap of 85 forced ~44
// VGPRs/thread of scratch spill = +184 MB HBM writes last round).
// Linear global I/O; LDS bounce hA in (17.4 KB), halved oA out (8.7 KB);
// LDS 26112 B/block -> up to 6 resident blocks/CU (VGPR permitting).
__global__ __launch_bounds__(256, 4) void fourier_main(
    const float* __restrict__ x, const float* __restrict__ alpha_p,
    const unsigned short* __restrict__ Gt, const float* __restrict__ C0,
    float* __restrict__ out) {
    __shared__ unsigned short hA[64 * PADW];  // bf16 tanh(alpha*x), full tile
    __shared__ unsigned short oA[32 * PADW];  // bf16 conv+C0, half tile bounce

    const int tid = threadIdx.x;
    const int lane = tid & 63;
    const int wid = tid >> 6;
    const int lrow = lane & 15;   // fragment row selector
    const int slot = lane >> 4;   // fragment k-chunk / col-group selector
    const int colb = wid * 32;

    const float a2 = 2.0f * alpha_p[0];
    const unsigned base = (unsigned)blockIdx.x * (64u * SIZE);  // max 33.5M < 2^31

    // linear map: thread tid, pass j <-> tile row j*8 + rl, cols cl..cl+3
    const int rl = tid >> 5;        // 0..7
    const int cl = (tid & 31) * 4;  // 0..124

    // ---- 1. contiguous x loads (kept in regs for the residual) ----
    float4 xr[8];
#pragma unroll
    for (int j = 0; j < 8; ++j)
        xr[j] = *reinterpret_cast<const float4*>(&x[base + j * 1024 + tid * 4]);

    // ---- 2. h = tanh(alpha*x) -> bf16 -> hA;  tanh(t) = 1 - 2/(1+e^{2t}) ----
#pragma unroll
    for (int j = 0; j < 8; ++j) {
        ushort4 hq;
        float e, r;
        e = __expf(a2 * xr[j].x); r = __builtin_amdgcn_rcpf(1.0f + e);
        hq.x = f2bf(fmaf(-2.0f, r, 1.0f));
        e = __expf(a2 * xr[j].y); r = __builtin_amdgcn_rcpf(1.0f + e);
        hq.y = f2bf(fmaf(-2.0f, r, 1.0f));
        e = __expf(a2 * xr[j].z); r = __builtin_amdgcn_rcpf(1.0f + e);
        hq.z = f2bf(fmaf(-2.0f, r, 1.0f));
        e = __expf(a2 * xr[j].w); r = __builtin_amdgcn_rcpf(1.0f + e);
        hq.w = f2bf(fmaf(-2.0f, r, 1.0f));
        *reinterpret_cast<ushort4*>(&hA[(j * 8 + rl) * PADW + cl]) = hq;
    }

    // ---- G fragments (8 KB/wave, L2-resident) + C0 for this wave's cols ----
    short8 gf[2][4];
    float4 c0v[2];
#pragma unroll
    for (int nt = 0; nt < 2; ++nt) {
        const int c = colb + nt * 16 + lrow;
#pragma unroll
        for (int kt = 0; kt < 4; ++kt)
            gf[nt][kt] = *reinterpret_cast<const short8*>(
                &Gt[c * SIZE + kt * 32 + slot * 8]);
        c0v[nt] = *reinterpret_cast<const float4*>(&C0[colb + nt * 16 + slot * 4]);
    }

    __syncthreads();  // B1: hA published

    // half-pass: MFMA rows [r0, r0+32) -> oA, then linear epilogue of the half
    auto conv_half = [&](int mt0) __attribute__((always_inline)) {
#pragma unroll
        for (int mt = mt0; mt < mt0 + 2; ++mt) {
            short8 hf[4];
#pragma unroll
            for (int kt = 0; kt < 4; ++kt)
                hf[kt] = *reinterpret_cast<const short8*>(
                    &hA[(mt * 16 + lrow) * PADW + kt * 32 + slot * 8]);
#pragma unroll
            for (int nt = 0; nt < 2; ++nt) {
                f32x4 a = {0.f, 0.f, 0.f, 0.f};
#pragma unroll
                for (int kt = 0; kt < 4; ++kt)
                    a = __builtin_amdgcn_mfma_f32_16x16x32_bf16(gf[nt][kt], hf[kt],
                                                                a, 0, 0, 0);
                // D: row = 16mt + lrow; cols = colb + 16nt + 4*slot + reg
                ushort4 o;
                o.x = f2bf(a[0] + c0v[nt].x);
                o.y = f2bf(a[1] + c0v[nt].y);
                o.z = f2bf(a[2] + c0v[nt].z);
                o.w = f2bf(a[3] + c0v[nt].w);
                *reinterpret_cast<ushort4*>(
                    &oA[((mt - mt0) * 16 + lrow) * PADW + colb + nt * 16 +
                        slot * 4]) = o;
            }
        }
    };
    auto epi_half = [&](int j0) __attribute__((always_inline)) {
#pragma unroll
        for (int j = j0; j < j0 + 4; ++j) {
            const ushort4 ov = *reinterpret_cast<const ushort4*>(
                &oA[((j - j0) * 8 + rl) * PADW + cl]);
            float4 r;
            r.x = bf2f(ov.x) + xr[j].x;
            r.y = bf2f(ov.y) + xr[j].y;
            r.z = bf2f(ov.z) + xr[j].z;
            r.w = bf2f(ov.w) + xr[j].w;
            *reinterpret_cast<float4*>(&out[base + j * 1024 + tid * 4]) = r;
        }
    };

    conv_half(0);          // rows 0..31 -> oA
    __syncthreads();       // B2: oA(half 0) published
    epi_half(0);           // store out rows 0..31
    __syncthreads();       // B3: all oA reads retired before overwrite
    conv_half(2);          // rows 32..63 -> oA
    __syncthreads();       // B4: oA(half 1) published
    epi_half(4);           // store out rows 32..63
}

extern "C" void kernel_launch(void* const* d_in, const int* in_sizes, int n_in,
                              void* d_out, int out_size, void* d_ws, size_t ws_size,
                              hipStream_t stream) {
    const float* x = (const float*)d_in[0];
    const float* alpha = (const float*)d_in[1];
    const float* dyt_w = (const float*)d_in[2];
    const float* dyt_b = (const float*)d_in[3];
    // d_in[4] = a_real, d_in[5] = a_imag, d_in[8] = ffn_bias: dead code in reference
    const float* b_real = (const float*)d_in[6];
    const float* b_imag = (const float*)d_in[7];
    float* out = (float*)d_out;

    unsigned short* Gt = (unsigned short*)d_ws;            // 32 KB bf16
    float* C0 = (float*)((char*)d_ws + SIZE * SIZE * 2);   // 512 B f32

    build_gt<<<1, 128, 0, stream>>>(b_real, b_imag, dyt_w, dyt_b, Gt, C0);

    const int rows = out_size / SIZE;   // 262144
    const int nblocks = rows / 64;      // 4096
    fourier_main<<<nblocks, 256, 0, stream>>>(x, alpha, Gt, C0, out);
}